// Round 5
// baseline (790.479 us; speedup 1.0000x reference)
//
#include <hip/hip_runtime.h>
#include <hip/hip_bf16.h>
#include <math.h>

#define B    512
#define INU  8
#define IC   1152
#define NU   10
#define US   16
#define JU   160            // NU*US
#define KI   9216           // INU*IC
#define BETAC 1.45f
#define NSPLIT 32
#define KC 288              // KI / NSPLIT; divides IC

typedef __attribute__((ext_vector_type(8))) __bf16 bf16x8;
typedef __attribute__((ext_vector_type(4))) float floatx4;

static __device__ __forceinline__ unsigned short f2bf(float f) {
  unsigned u = __builtin_bit_cast(unsigned, f);
  u = (u + 0x7fffu + ((u >> 16) & 1u)) >> 16;   // RNE
  return (unsigned short)u;
}
static __device__ __forceinline__ float bf2f(unsigned short h) {
  return __builtin_bit_cast(float, ((unsigned)h) << 16);
}
static __device__ __forceinline__ uint4 scale8(uint4 wv, float4 cA, float4 cB) {
  union { uint4 u; unsigned short s[8]; } in;
  in.u = wv;
  union { uint4 u; __hip_bfloat162 h[4]; } o;
  o.h[0] = __float22bfloat162_rn(make_float2(bf2f(in.s[0]) * cA.x, bf2f(in.s[1]) * cA.y));
  o.h[1] = __float22bfloat162_rn(make_float2(bf2f(in.s[2]) * cA.z, bf2f(in.s[3]) * cA.w));
  o.h[2] = __float22bfloat162_rn(make_float2(bf2f(in.s[4]) * cB.x, bf2f(in.s[5]) * cB.y));
  o.h[3] = __float22bfloat162_rn(make_float2(bf2f(in.s[6]) * cB.z, bf2f(in.s[7]) * cB.w));
  return o.u;
}

// ======================= cooperative mega-kernel ===========================
// sync area (u32, memset 0 each call): [0]=bar_cnt [1]=bar_gen
//   tile_cnt(it,tb) = sync[16 + (it*16+tb)*16]   (it<3, tb<16, padded)
//   bp_cnt(it)      = sync[896 + it*16]          (it<2)
// ===========================================================================

union alignas(16) SharedU {
  float ts[64 * 65];                                             // prep
  struct { unsigned short xs[32 * 40]; unsigned short ms[160 * 40];
           float cs[NU * KC]; } sg;                              // s_gemm
  struct { unsigned short xs[64 * 40]; unsigned short vs[160 * 40]; } bu;
  struct { float bsum[IC]; float red[256]; } sm;                 // softmax
  struct { float sv[JU]; float fac[US]; } sq;                    // squash
};

__device__ __forceinline__ void gbar(unsigned* syncp, unsigned nb) {
  __syncthreads();
  if (threadIdx.x == 0) {
    __threadfence();
    unsigned g = __hip_atomic_load(&syncp[1], __ATOMIC_SEQ_CST,
                                   __HIP_MEMORY_SCOPE_AGENT);
    unsigned a = __hip_atomic_fetch_add(&syncp[0], 1u, __ATOMIC_SEQ_CST,
                                        __HIP_MEMORY_SCOPE_AGENT);
    if (a == nb - 1) {
      __hip_atomic_store(&syncp[0], 0u, __ATOMIC_SEQ_CST,
                         __HIP_MEMORY_SCOPE_AGENT);
      __hip_atomic_fetch_add(&syncp[1], 1u, __ATOMIC_SEQ_CST,
                             __HIP_MEMORY_SCOPE_AGENT);
    } else {
      while (__hip_atomic_load(&syncp[1], __ATOMIC_SEQ_CST,
                               __HIP_MEMORY_SCOPE_AGENT) == g)
        __builtin_amdgcn_s_sleep(4);
    }
    __threadfence();
  }
  __syncthreads();
}

__device__ __forceinline__ void arrive(unsigned* p) {
  __syncthreads();
  if (threadIdx.x == 0) { __threadfence(); atomicAdd(p, 1u); }
}

__device__ __forceinline__ void spin_until(unsigned* p, unsigned target) {
  if (threadIdx.x == 0) {
    while (__hip_atomic_load(p, __ATOMIC_SEQ_CST,
                             __HIP_MEMORY_SCOPE_AGENT) < target)
      __builtin_amdgcn_s_sleep(2);
  }
  __syncthreads();
  __threadfence();
}

__global__ __launch_bounds__(256, 2) void caps_mega(
    const float* __restrict__ x, const float* __restrict__ W,
    float* __restrict__ out, unsigned* __restrict__ syncp,
    float* __restrict__ cT, float* __restrict__ bp, float* __restrict__ sp,
    unsigned short* __restrict__ xb, unsigned short* __restrict__ xT,
    unsigned short* __restrict__ Wt, unsigned short* __restrict__ vT) {
  const unsigned nb = gridDim.x;
  const unsigned bid = blockIdx.x;
  const int t = threadIdx.x;
  const int lane = t & 63, w = t >> 6, col = lane & 15, quad = lane >> 4;
  __shared__ SharedU sh;

  // ---------------- phase 0: prep ----------------
  for (unsigned task = bid; task < 1152; task += nb) {
    int k0 = (int)(task % 144) * 64;
    int b0 = (int)(task / 144) * 64;
    __syncthreads();
#pragma unroll
    for (int r = 0; r < 16; ++r) {
      int idx = t + 256 * r;
      int br = idx >> 6, kc = idx & 63;
      float v = x[(size_t)(b0 + br) * KI + k0 + kc];
      sh.ts[br * 65 + kc] = v;
      xb[(size_t)(b0 + br) * KI + k0 + kc] = f2bf(v);
    }
    __syncthreads();
#pragma unroll
    for (int r = 0; r < 8; ++r) {
      int idx = t + 256 * r;
      int kr = idx >> 5, bc = (idx & 31) * 2;
      unsigned lo = f2bf(sh.ts[bc * 65 + kr]);
      unsigned hi = f2bf(sh.ts[(bc + 1) * 65 + kr]);
      *(unsigned*)&xT[(size_t)(k0 + kr) * B + b0 + bc] = lo | (hi << 16);
    }
  }
  for (unsigned task = 1152 + bid; task < 6912; task += nb) {
    int e = (int)(task - 1152) * 256 + t;
    int ju = e / KI;
    int rem = e - ju * KI;
    int k = rem / IC;
    int i = rem - k * IC;
    Wt[e] = f2bf(W[(size_t)i * 1280 + ju * 8 + k]);
  }
  gbar(syncp, nb);

  for (int it = 0; it < 3; ++it) {
    // ---------------- s_gemm (512 tasks: 16 b-tiles x 32 k-chunks) --------
    for (unsigned task = bid; task < 512; task += nb) {
      int tb = (int)(task & 15), y = (int)(task >> 4);
      int b0 = tb * 32;
      int kbase = y * KC;
      int i0 = (y & 3) * KC;     // kbase % IC
      __syncthreads();           // LDS reuse guard
      if (it == 0) {
        for (int c = t; c < NU * KC; c += 256) sh.sg.cs[c] = 1.0f / (float)IC;
      } else {
        for (int c = t; c < NU * KC; c += 256) {
          int j = c / KC;
          sh.sg.cs[c] = cT[j * IC + i0 + (c - j * KC)];
        }
      }
      int mc = (t & 3) * 8;
      int mrow0 = t >> 2, mrow1 = (t + 256) >> 2, mrow2 = (t + 512) >> 2;
      int j0 = mrow0 >> 4, j1 = mrow1 >> 4, j2 = mrow2 >> 4;
      uint4 xv, m0, m1, m2;
      auto prefetch = [&](int kk) {
        if (t < 128) xv = *(const uint4*)&xb[(size_t)(b0 + mrow0) * KI + kk + mc];
        m0 = *(const uint4*)&Wt[(size_t)mrow0 * KI + kk + mc];
        m1 = *(const uint4*)&Wt[(size_t)mrow1 * KI + kk + mc];
        if (t < 128) m2 = *(const uint4*)&Wt[(size_t)mrow2 * KI + kk + mc];
      };
      auto commit = [&](int off) {
        if (t < 128) *(uint4*)&sh.sg.xs[mrow0 * 40 + mc] = xv;
        float4 a0 = *(const float4*)&sh.sg.cs[j0 * KC + off + mc];
        float4 a1 = *(const float4*)&sh.sg.cs[j0 * KC + off + mc + 4];
        *(uint4*)&sh.sg.ms[mrow0 * 40 + mc] = scale8(m0, a0, a1);
        float4 c0 = *(const float4*)&sh.sg.cs[j1 * KC + off + mc];
        float4 c1 = *(const float4*)&sh.sg.cs[j1 * KC + off + mc + 4];
        *(uint4*)&sh.sg.ms[mrow1 * 40 + mc] = scale8(m1, c0, c1);
        if (t < 128) {
          float4 d0 = *(const float4*)&sh.sg.cs[j2 * KC + off + mc];
          float4 d1 = *(const float4*)&sh.sg.cs[j2 * KC + off + mc + 4];
          *(uint4*)&sh.sg.ms[mrow2 * 40 + mc] = scale8(m2, d0, d1);
        }
      };
      floatx4 acc[5];
#pragma unroll
      for (int jj = 0; jj < 5; ++jj) acc[jj] = (floatx4){0.f, 0.f, 0.f, 0.f};
      int jb = (w >> 1) * 5;
      int arow = ((w & 1) * 16 + col) * 40 + quad * 8;

      prefetch(kbase);
      __syncthreads();           // cs ready
#pragma unroll 1
      for (int s = 0; s < KC / 32; ++s) {
        commit(s * 32);
        __syncthreads();
        if (s + 1 < KC / 32) prefetch(kbase + (s + 1) * 32);
        bf16x8 a = *(bf16x8*)&sh.sg.xs[arow];
#pragma unroll
        for (int jj = 0; jj < 5; ++jj) {
          bf16x8 bb = *(bf16x8*)&sh.sg.ms[((jb + jj) * 16 + col) * 40 + quad * 8];
          acc[jj] = __builtin_amdgcn_mfma_f32_16x16x32_bf16(a, bb, acc[jj], 0, 0, 0);
        }
        __syncthreads();
      }
#pragma unroll
      for (int jj = 0; jj < 5; ++jj)
#pragma unroll
        for (int r = 0; r < 4; ++r) {
          int b = b0 + (w & 1) * 16 + quad * 4 + r;
          sp[((size_t)y * B + b) * JU + (jb + jj) * 16 + col] = acc[jj][r];
        }
      arrive(&syncp[16 + (it * 16 + tb) * 16]);
    }
    // ---------------- squash (512 tasks, one b each) ----------------------
    for (unsigned sb = bid; sb < 512; sb += nb) {
      int tile = (int)(sb >> 5);
      spin_until(&syncp[16 + (it * 16 + tile) * 16], 32u);
      float s = 0.0f;
      if (t < JU) {
#pragma unroll
        for (int y = 0; y < NSPLIT; ++y)
          s += sp[((size_t)y * B + sb) * JU + t];
        sh.sq.sv[t] = s;
      }
      __syncthreads();
      if (t < US) {
        float m = 0.0f;
#pragma unroll
        for (int j = 0; j < NU; ++j) {
          float q = sh.sq.sv[j * US + t];
          m += q * q;
        }
        sh.sq.fac[t] = sqrtf(m) / (BETAC + m);
      }
      __syncthreads();
      if (t < JU) {
        float val = s * sh.sq.fac[t & 15];
        vT[(size_t)t * B + sb] = f2bf(val);
        if (it == 2) out[(size_t)sb * JU + t] = val;
      }
      __syncthreads();
    }
    if (it == 2) break;
    gbar(syncp, nb);

    // ---------------- b_update (288 tasks) --------------------------------
    for (unsigned task = bid; task < 288; task += nb) {
      int k = (int)(task / 36);
      int rem = (int)(task % 36);
      int i0 = (rem >> 1) * 64;
      int bs = rem & 1;
      size_t ki0 = (size_t)k * IC + i0;
      __syncthreads();           // LDS reuse guard
      int mc = (t & 3) * 8;
      int mrow0 = t >> 2, mrow1 = (t + 256) >> 2, mrow2 = (t + 512) >> 2;
      uint4 xv, m0, m1, m2;
      auto prefetch = [&](int c0) {
        xv = *(const uint4*)&xT[(ki0 + mrow0) * B + c0 + mc];
        m0 = *(const uint4*)&vT[(size_t)mrow0 * B + c0 + mc];
        m1 = *(const uint4*)&vT[(size_t)mrow1 * B + c0 + mc];
        if (t < 128) m2 = *(const uint4*)&vT[(size_t)mrow2 * B + c0 + mc];
      };
      auto commit = [&]() {
        *(uint4*)&sh.bu.xs[mrow0 * 40 + mc] = xv;
        *(uint4*)&sh.bu.vs[mrow0 * 40 + mc] = m0;
        *(uint4*)&sh.bu.vs[mrow1 * 40 + mc] = m1;
        if (t < 128) *(uint4*)&sh.bu.vs[mrow2 * 40 + mc] = m2;
      };
      floatx4 acc[10];
#pragma unroll
      for (int jt = 0; jt < 10; ++jt) acc[jt] = (floatx4){0.f, 0.f, 0.f, 0.f};
      prefetch(bs * 256);
#pragma unroll 1
      for (int s = 0; s < 8; ++s) {
        commit();
        __syncthreads();
        if (s < 7) prefetch(bs * 256 + (s + 1) * 32);
        bf16x8 a = *(bf16x8*)&sh.bu.xs[(w * 16 + col) * 40 + quad * 8];
#pragma unroll
        for (int jt = 0; jt < 10; ++jt) {
          bf16x8 bb = *(bf16x8*)&sh.bu.vs[(jt * 16 + col) * 40 + quad * 8];
          acc[jt] = __builtin_amdgcn_mfma_f32_16x16x32_bf16(a, bb, acc[jt], 0, 0, 0);
        }
        __syncthreads();
      }
      int p = k * 2 + bs;
#pragma unroll
      for (int jt = 0; jt < 10; ++jt) {
#pragma unroll
        for (int r = 0; r < 4; ++r) {
          int i = i0 + w * 16 + quad * 4 + r;
          float wv = W[(size_t)i * 1280 + jt * 128 + col * 8 + k];
          float pr = wv * acc[jt][r];
          pr += __shfl_xor(pr, 1);
          pr += __shfl_xor(pr, 2);
          pr += __shfl_xor(pr, 4);
          pr += __shfl_xor(pr, 8);
          if (col == 0)
            bp[(size_t)p * (IC * NU) + jt * IC + i] = pr * (1.0f / (float)B);
        }
      }
      arrive(&syncp[896 + it * 16]);
    }
    // ---------------- fused softmax (blocks 0..9, one j each) -------------
    if (bid < 10) {
      spin_until(&syncp[896 + it * 16], 288u);
      int j = (int)bid;
      for (int i = t; i < IC; i += 256) {
        float s = 0.0f;
#pragma unroll
        for (int p = 0; p < 16; ++p)
          s += bp[(size_t)p * (IC * NU) + j * IC + i];
        sh.sm.bsum[i] = s;
      }
      __syncthreads();
      float m = -1e30f;
      for (int i = t; i < IC; i += 256) m = fmaxf(m, sh.sm.bsum[i]);
      sh.sm.red[t] = m;
      __syncthreads();
      for (int o = 128; o > 0; o >>= 1) {
        if (t < o) sh.sm.red[t] = fmaxf(sh.sm.red[t], sh.sm.red[t + o]);
        __syncthreads();
      }
      float mx = sh.sm.red[0];
      __syncthreads();
      float sm = 0.0f;
      for (int i = t; i < IC; i += 256) {
        float e = __expf(sh.sm.bsum[i] - mx);
        sh.sm.bsum[i] = e;
        sm += e;
      }
      sh.sm.red[t] = sm;
      __syncthreads();
      for (int o = 128; o > 0; o >>= 1) {
        if (t < o) sh.sm.red[t] += sh.sm.red[t + o];
        __syncthreads();
      }
      float inv = 1.0f / sh.sm.red[0];
      __syncthreads();
      for (int i = t; i < IC; i += 256) cT[(size_t)j * IC + i] = sh.sm.bsum[i] * inv;
    }
    gbar(syncp, nb);
  }
}

// ==================== fallback path (round-4, proven) ======================
__global__ __launch_bounds__(256) void prep_kernel(
    const float* __restrict__ x, const float* __restrict__ W,
    unsigned short* __restrict__ xb, unsigned short* __restrict__ xT,
    unsigned short* __restrict__ Wt, float* __restrict__ cT) {
  __shared__ float ts[64 * 65];
  int id = blockIdx.x;
  int t = threadIdx.x;
  if (id < 1152) {
    int k0 = (id % 144) * 64;
    int b0 = (id / 144) * 64;
#pragma unroll
    for (int r = 0; r < 16; ++r) {
      int idx = t + 256 * r;
      int br = idx >> 6, kc = idx & 63;
      float v = x[(size_t)(b0 + br) * KI + k0 + kc];
      ts[br * 65 + kc] = v;
      xb[(size_t)(b0 + br) * KI + k0 + kc] = f2bf(v);
    }
    __syncthreads();
#pragma unroll
    for (int r = 0; r < 8; ++r) {
      int idx = t + 256 * r;
      int kr = idx >> 5, bc = (idx & 31) * 2;
      unsigned lo = f2bf(ts[bc * 65 + kr]);
      unsigned hi = f2bf(ts[(bc + 1) * 65 + kr]);
      *(unsigned*)&xT[(size_t)(k0 + kr) * B + b0 + bc] = lo | (hi << 16);
    }
  } else {
    int e = (id - 1152) * 256 + t;
    int ju = e / KI;
    int rem = e - ju * KI;
    int k = rem / IC;
    int i = rem - k * IC;
    Wt[e] = f2bf(W[(size_t)i * 1280 + ju * 8 + k]);
    if (id == 1152) {
      for (int q = t; q < IC * NU; q += 256) cT[q] = 1.0f / (float)IC;
    }
  }
}

__global__ __launch_bounds__(256) void s_gemm_mfma(
    const unsigned short* __restrict__ xb, const unsigned short* __restrict__ Wt,
    const float* __restrict__ cT, float* __restrict__ sp) {
  int b0 = blockIdx.x * 64;
  int kbase = blockIdx.y * KC;
  int i0 = kbase % IC;
  int t = threadIdx.x;
  int w = t >> 6, lane = t & 63, col = lane & 15, quad = lane >> 4;
  __shared__ unsigned short xs[64 * 40];
  __shared__ unsigned short ms[160 * 40];
  __shared__ float cs[NU * KC];

  int xrow = t >> 2, xc = (t & 3) * 8;
  int mrow0 = t >> 2, mrow1 = (t + 256) >> 2, mrow2 = (t + 512) >> 2;
  int mc = (t & 3) * 8;
  int j0 = mrow0 >> 4, j1 = mrow1 >> 4, j2 = mrow2 >> 4;

  for (int ch = t; ch < NU * KC; ch += 256) {
    int j = ch / KC;
    cs[ch] = cT[j * IC + i0 + (ch - j * KC)];
  }
  uint4 xv, m0, m1, m2;
  auto prefetch = [&](int k0) {
    xv = *(const uint4*)&xb[(size_t)(b0 + xrow) * KI + k0 + xc];
    m0 = *(const uint4*)&Wt[(size_t)mrow0 * KI + k0 + mc];
    m1 = *(const uint4*)&Wt[(size_t)mrow1 * KI + k0 + mc];
    if (t < 128) m2 = *(const uint4*)&Wt[(size_t)mrow2 * KI + k0 + mc];
  };
  auto commit = [&](int off) {
    *(uint4*)&xs[xrow * 40 + xc] = xv;
    float4 a0 = *(const float4*)&cs[j0 * KC + off + mc];
    float4 a1 = *(const float4*)&cs[j0 * KC + off + mc + 4];
    *(uint4*)&ms[mrow0 * 40 + mc] = scale8(m0, a0, a1);
    float4 b0c = *(const float4*)&cs[j1 * KC + off + mc];
    float4 b1c = *(const float4*)&cs[j1 * KC + off + mc + 4];
    *(uint4*)&ms[mrow1 * 40 + mc] = scale8(m1, b0c, b1c);
    if (t < 128) {
      float4 d0 = *(const float4*)&cs[j2 * KC + off + mc];
      float4 d1 = *(const float4*)&cs[j2 * KC + off + mc + 4];
      *(uint4*)&ms[mrow2 * 40 + mc] = scale8(m2, d0, d1);
    }
  };
  floatx4 acc[10];
#pragma unroll
  for (int jt = 0; jt < 10; ++jt) acc[jt] = (floatx4){0.f, 0.f, 0.f, 0.f};
  prefetch(kbase);
  __syncthreads();
  const int nsteps = KC >> 5;
  for (int s = 0; s < nsteps; ++s) {
    commit(s * 32);
    __syncthreads();
    if (s + 1 < nsteps) prefetch(kbase + (s + 1) * 32);
    bf16x8 a = *(bf16x8*)&xs[(w * 16 + col) * 40 + quad * 8];
#pragma unroll
    for (int jt = 0; jt < 10; ++jt) {
      bf16x8 bb = *(bf16x8*)&ms[(jt * 16 + col) * 40 + quad * 8];
      acc[jt] = __builtin_amdgcn_mfma_f32_16x16x32_bf16(a, bb, acc[jt], 0, 0, 0);
    }
    __syncthreads();
  }
#pragma unroll
  for (int jt = 0; jt < 10; ++jt)
#pragma unroll
    for (int r = 0; r < 4; ++r) {
      int b = b0 + w * 16 + quad * 4 + r;
      sp[((size_t)blockIdx.y * B + b) * JU + jt * 16 + col] = acc[jt][r];
    }
}

__global__ __launch_bounds__(192) void squash_kernel(
    const float* __restrict__ sp, unsigned short* __restrict__ vT,
    float* __restrict__ out) {
  int b = blockIdx.x;
  int t = threadIdx.x;
  __shared__ float sv[JU];
  __shared__ float fac[US];
  float s = 0.0f;
  if (t < JU) {
#pragma unroll
    for (int k = 0; k < NSPLIT; ++k) s += sp[((size_t)k * B + b) * JU + t];
    sv[t] = s;
  }
  __syncthreads();
  if (t < US) {
    float m = 0.0f;
#pragma unroll
    for (int j = 0; j < NU; ++j) {
      float q = sv[j * US + t];
      m += q * q;
    }
    fac[t] = sqrtf(m) / (BETAC + m);
  }
  __syncthreads();
  if (t < JU) {
    float val = s * fac[t & 15];
    vT[(size_t)t * B + b] = f2bf(val);
    if (out) out[(size_t)b * JU + t] = val;
  }
}

__global__ __launch_bounds__(256) void b_update_mfma(
    const unsigned short* __restrict__ xT, const unsigned short* __restrict__ vT,
    const float* __restrict__ W, float* __restrict__ bp) {
  int k = blockIdx.x / 18;
  int i0 = (blockIdx.x - k * 18) * 64;
  int bs = blockIdx.y;
  size_t ki0 = (size_t)k * IC + i0;
  int t = threadIdx.x;
  int w = t >> 6, lane = t & 63, col = lane & 15, quad = lane >> 4;
  __shared__ unsigned short xs[64 * 40];
  __shared__ unsigned short vs[160 * 40];
  int xrow = t >> 2, xc = (t & 3) * 8;
  int mrow0 = t >> 2, mrow1 = (t + 256) >> 2, mrow2 = (t + 512) >> 2;
  int mc = (t & 3) * 8;
  uint4 xv, m0, m1, m2;
  auto prefetch = [&](int c0) {
    xv = *(const uint4*)&xT[(ki0 + xrow) * B + c0 + xc];
    m0 = *(const uint4*)&vT[(size_t)mrow0 * B + c0 + mc];
    m1 = *(const uint4*)&vT[(size_t)mrow1 * B + c0 + mc];
    if (t < 128) m2 = *(const uint4*)&vT[(size_t)mrow2 * B + c0 + mc];
  };
  auto commit = [&]() {
    *(uint4*)&xs[xrow * 40 + xc] = xv;
    *(uint4*)&vs[mrow0 * 40 + mc] = m0;
    *(uint4*)&vs[mrow1 * 40 + mc] = m1;
    if (t < 128) *(uint4*)&vs[mrow2 * 40 + mc] = m2;
  };
  floatx4 acc[10];
#pragma unroll
  for (int jt = 0; jt < 10; ++jt) acc[jt] = (floatx4){0.f, 0.f, 0.f, 0.f};
  prefetch(bs * 256);
  for (int s = 0; s < 8; ++s) {
    commit();
    __syncthreads();
    if (s < 7) prefetch(bs * 256 + (s + 1) * 32);
    bf16x8 a = *(bf16x8*)&xs[(w * 16 + col) * 40 + quad * 8];
#pragma unroll
    for (int jt = 0; jt < 10; ++jt) {
      bf16x8 bb = *(bf16x8*)&vs[(jt * 16 + col) * 40 + quad * 8];
      acc[jt] = __builtin_amdgcn_mfma_f32_16x16x32_bf16(a, bb, acc[jt], 0, 0, 0);
    }
    __syncthreads();
  }
  int p = k * 2 + bs;
#pragma unroll
  for (int jt = 0; jt < 10; ++jt) {
#pragma unroll
    for (int r = 0; r < 4; ++r) {
      int i = i0 + w * 16 + quad * 4 + r;
      float wv = W[(size_t)i * 1280 + jt * 128 + col * 8 + k];
      float pr = wv * acc[jt][r];
      pr += __shfl_xor(pr, 1);
      pr += __shfl_xor(pr, 2);
      pr += __shfl_xor(pr, 4);
      pr += __shfl_xor(pr, 8);
      if (col == 0)
        bp[(size_t)p * (IC * NU) + jt * IC + i] = pr * (1.0f / (float)B);
    }
  }
}

__global__ __launch_bounds__(256) void softmax_c_kernel(
    const float* __restrict__ bp, float* __restrict__ cT) {
  int j = blockIdx.x;
  int t = threadIdx.x;
  __shared__ float bsum[IC];
  __shared__ float red[256];
  for (int i = t; i < IC; i += 256) {
    float s = 0.0f;
#pragma unroll
    for (int p = 0; p < 16; ++p) s += bp[(size_t)p * (IC * NU) + j * IC + i];
    bsum[i] = s;
  }
  __syncthreads();
  float m = -1e30f;
  for (int i = t; i < IC; i += 256) m = fmaxf(m, bsum[i]);
  red[t] = m;
  __syncthreads();
  for (int o = 128; o > 0; o >>= 1) {
    if (t < o) red[t] = fmaxf(red[t], red[t + o]);
    __syncthreads();
  }
  float mx = red[0];
  __syncthreads();
  float sm = 0.0f;
  for (int i = t; i < IC; i += 256) {
    float e = __expf(bsum[i] - mx);
    bsum[i] = e;
    sm += e;
  }
  red[t] = sm;
  __syncthreads();
  for (int o = 128; o > 0; o >>= 1) {
    if (t < o) red[t] += red[t + o];
    __syncthreads();
  }
  float inv = 1.0f / red[0];
  for (int i = t; i < IC; i += 256) cT[(size_t)j * IC + i] = bsum[i] * inv;
}

// ---------------------------------------------------------------------------
extern "C" void kernel_launch(void* const* d_in, const int* in_sizes, int n_in,
                              void* d_out, int out_size, void* d_ws,
                              size_t ws_size, hipStream_t stream) {
  const float* x = (const float*)d_in[0];   // (512, 8, 1152)
  const float* W = (const float*)d_in[1];   // (1152, 10, 16, 8)
  float* out = (float*)d_out;               // (512, 10, 16)

  char* pws = (char*)d_ws;
  unsigned* syncp = (unsigned*)pws;            pws += 4096;
  float* cT = (float*)pws;                     pws += (size_t)NU * IC * 4;
  float* bp = (float*)pws;                     pws += (size_t)16 * IC * NU * 4;
  float* sp = (float*)pws;                     pws += (size_t)NSPLIT * B * JU * 4;
  unsigned short* xb = (unsigned short*)pws;   pws += (size_t)B * KI * 2;
  unsigned short* xT = (unsigned short*)pws;   pws += (size_t)KI * B * 2;
  unsigned short* Wt = (unsigned short*)pws;   pws += (size_t)JU * KI * 2;
  unsigned short* vT = (unsigned short*)pws;

  int maxb = 0;
  hipError_t qerr =
      hipOccupancyMaxActiveBlocksPerMultiprocessor(&maxb, caps_mega, 256, 0);
  int nblk = (qerr == hipSuccess) ? maxb * 256 : 0;
  if (nblk > 512) nblk = 512;

  if (nblk >= 64) {
    hipMemsetAsync(syncp, 0, 4096, stream);
    void* args[] = {(void*)&x, (void*)&W, (void*)&out, (void*)&syncp,
                    (void*)&cT, (void*)&bp, (void*)&sp, (void*)&xb,
                    (void*)&xT, (void*)&Wt, (void*)&vT};
    hipError_t lerr = hipLaunchCooperativeKernel(
        caps_mega, dim3(nblk), dim3(256), args, 0, stream);
    if (lerr == hipSuccess) return;
  }

  // fallback: proven round-4 multi-launch path
  prep_kernel<<<1152 + 5760, 256, 0, stream>>>(x, W, xb, xT, Wt, cT);
  for (int it = 0; it < 3; ++it) {
    s_gemm_mfma<<<dim3(8, NSPLIT), 256, 0, stream>>>(xb, Wt, cT, sp);
    squash_kernel<<<B, 192, 0, stream>>>(sp, vT, (it == 2) ? out : nullptr);
    if (it < 2) {
      b_update_mfma<<<dim3(144, 2), 256, 0, stream>>>(xT, vT, W, bp);
      softmax_c_kernel<<<NU, 256, 0, stream>>>(bp, cT);
    }
  }
}

// Round 6
// 177.009 us; speedup vs baseline: 4.4658x; 4.4658x over previous
//
#include <hip/hip_runtime.h>
#include <hip/hip_bf16.h>
#include <math.h>

#define B    512
#define INU  8
#define IC   1152
#define NU   10
#define US   16
#define JU   160            // NU*US
#define KI   9216           // INU*IC
#define BETAC 1.45f
#define NSPLIT 32
#define KC 288              // KI / NSPLIT; divides IC

typedef __attribute__((ext_vector_type(8))) __bf16 bf16x8;
typedef __attribute__((ext_vector_type(4))) float floatx4;

static __device__ __forceinline__ unsigned short f2bf(float f) {
  unsigned u = __builtin_bit_cast(unsigned, f);
  u = (u + 0x7fffu + ((u >> 16) & 1u)) >> 16;   // RNE
  return (unsigned short)u;
}
static __device__ __forceinline__ float bf2f(unsigned short h) {
  return __builtin_bit_cast(float, ((unsigned)h) << 16);
}
// 8 bf16 * 8 fp32 scale -> 8 bf16 (packed RNE converts)
static __device__ __forceinline__ uint4 scale8(uint4 wv, float4 cA, float4 cB) {
  union { uint4 u; unsigned short s[8]; } in;
  in.u = wv;
  union { uint4 u; __hip_bfloat162 h[4]; } o;
  o.h[0] = __float22bfloat162_rn(make_float2(bf2f(in.s[0]) * cA.x, bf2f(in.s[1]) * cA.y));
  o.h[1] = __float22bfloat162_rn(make_float2(bf2f(in.s[2]) * cA.z, bf2f(in.s[3]) * cA.w));
  o.h[2] = __float22bfloat162_rn(make_float2(bf2f(in.s[4]) * cB.x, bf2f(in.s[5]) * cB.y));
  o.h[3] = __float22bfloat162_rn(make_float2(bf2f(in.s[6]) * cB.z, bf2f(in.s[7]) * cB.w));
  return o.u;
}

// ---------------------------------------------------------------------------
// prep (one-time):
//  blocks [0,1152): x fp32 [b][ki] -> xb bf16 [b][ki] + xT bf16 [ki][b]
//    (64x64 LDS transpose, pad 65).
//  blocks [1152,1296): W LDS-tiled pass, 32 i x 320 c tiles (pad 322 ->
//    <=2-way conflicts = free):
//      Wt bf16 [ju][k*IC+i]   (MFMA B-operand layout, coalesced both sides)
//      Wr fp32 [k*IC+i][ju]   (coalesced epilogue reads in b_update)
//    Block 1152 also inits cT = 1/IC (softmax of zero logits).
// ---------------------------------------------------------------------------
__global__ __launch_bounds__(256) void prep_kernel(
    const float* __restrict__ x, const float* __restrict__ W,
    unsigned short* __restrict__ xb, unsigned short* __restrict__ xT,
    unsigned short* __restrict__ Wt, float* __restrict__ Wr,
    float* __restrict__ cT) {
  __shared__ float ts[32 * 322];    // 41.2 KB (x-part uses first 64*65)
  int id = blockIdx.x;
  int t = threadIdx.x;
  if (id < 1152) {
    int k0 = (id % 144) * 64;
    int b0 = (id / 144) * 64;
#pragma unroll
    for (int r = 0; r < 16; ++r) {
      int idx = t + 256 * r;
      int br = idx >> 6, kc = idx & 63;
      float v = x[(size_t)(b0 + br) * KI + k0 + kc];
      ts[br * 65 + kc] = v;
      xb[(size_t)(b0 + br) * KI + k0 + kc] = f2bf(v);
    }
    __syncthreads();
#pragma unroll
    for (int r = 0; r < 8; ++r) {
      int idx = t + 256 * r;            // 0..2047
      int kr = idx >> 5, bc = (idx & 31) * 2;
      unsigned lo = f2bf(ts[bc * 65 + kr]);
      unsigned hi = f2bf(ts[(bc + 1) * 65 + kr]);
      *(unsigned*)&xT[(size_t)(k0 + kr) * B + b0 + bc] = lo | (hi << 16);
    }
  } else {
    int wid = id - 1152;              // 0..143
    int i0 = (wid >> 2) * 32;         // 36 i-chunks
    int c0 = (wid & 3) * 320;         // 4 c-chunks of W's 1280-wide rows
    // load 32 x 320 tile, coalesced (float2, pad 322 keeps 8B align)
#pragma unroll
    for (int r = 0; r < 20; ++r) {
      int q = t + 256 * r;            // < 5120 float2
      int il = q / 160, c = (q - il * 160) * 2;
      *(float2*)&ts[il * 322 + c] =
          *(const float2*)&W[(size_t)(i0 + il) * 1280 + c0 + c];
    }
    __syncthreads();
    // Wt: for each col pair p (ju,k), write 32 i as bf16 (coalesced ushort2)
    {
      int il2 = (t & 15) * 2;
      for (int p = (t >> 4); p < 320; p += 16) {
        int c = c0 + p;
        int ju = c >> 3, k = c & 7;
        unsigned lo = f2bf(ts[il2 * 322 + p]);
        unsigned hi = f2bf(ts[(il2 + 1) * 322 + p]);
        *(unsigned*)&Wt[(size_t)ju * KI + k * IC + i0 + il2] = lo | (hi << 16);
      }
    }
    // Wr[k*IC+i][ju]: 40-float contiguous runs per (k,i)
    int ju0 = c0 >> 3;
    for (int q = t; q < 8 * 32 * 40; q += 256) {
      int k = q / 1280;
      int il = (q / 40) & 31;
      int jl = q - (q / 40) * 40;
      Wr[((size_t)k * IC + i0 + il) * JU + ju0 + jl] = ts[il * 322 + jl * 8 + k];
    }
    if (id == 1152) {
      for (int q = t; q < IC * NU; q += 256) cT[q] = 1.0f / (float)IC;
    }
  }
}

// ---------------------------------------------------------------------------
// s_gemm (MFMA, fused c-scale from LDS, reg double-buffered):
// sp[y][b][ju] = sum_{ki in chunk y} xb[b,ki] * (Wt[ju,ki] * cT[j, i(ki)])
// Grid: (8 b-tiles of 64, NSPLIT) x 256 (4 waves; wave = 16 b x 160 ju).
// ---------------------------------------------------------------------------
__global__ __launch_bounds__(256) void s_gemm_mfma(
    const unsigned short* __restrict__ xb, const unsigned short* __restrict__ Wt,
    const float* __restrict__ cT, float* __restrict__ sp) {
  int b0 = blockIdx.x * 64;
  int kbase = blockIdx.y * KC;
  int i0 = kbase % IC;
  int t = threadIdx.x;
  int w = t >> 6, lane = t & 63, col = lane & 15, quad = lane >> 4;
  __shared__ unsigned short xs[64 * 40];    // pad 40: <=2-way (free)
  __shared__ unsigned short ms[160 * 40];
  __shared__ float cs[NU * KC];             // 11.5 KB

  int xrow = t >> 2, xc = (t & 3) * 8;
  int mrow0 = t >> 2, mrow1 = (t + 256) >> 2, mrow2 = (t + 512) >> 2;
  int mc = (t & 3) * 8;
  int j0 = mrow0 >> 4, j1 = mrow1 >> 4, j2 = mrow2 >> 4;

  for (int ch = t; ch < NU * KC; ch += 256) {
    int j = ch / KC;
    cs[ch] = cT[j * IC + i0 + (ch - j * KC)];
  }
  uint4 xv, m0, m1, m2;
  auto prefetch = [&](int k0) {
    xv = *(const uint4*)&xb[(size_t)(b0 + xrow) * KI + k0 + xc];
    m0 = *(const uint4*)&Wt[(size_t)mrow0 * KI + k0 + mc];
    m1 = *(const uint4*)&Wt[(size_t)mrow1 * KI + k0 + mc];
    if (t < 128) m2 = *(const uint4*)&Wt[(size_t)mrow2 * KI + k0 + mc];
  };
  auto commit = [&](int off) {
    *(uint4*)&xs[xrow * 40 + xc] = xv;
    float4 a0 = *(const float4*)&cs[j0 * KC + off + mc];
    float4 a1 = *(const float4*)&cs[j0 * KC + off + mc + 4];
    *(uint4*)&ms[mrow0 * 40 + mc] = scale8(m0, a0, a1);
    float4 b0c = *(const float4*)&cs[j1 * KC + off + mc];
    float4 b1c = *(const float4*)&cs[j1 * KC + off + mc + 4];
    *(uint4*)&ms[mrow1 * 40 + mc] = scale8(m1, b0c, b1c);
    if (t < 128) {
      float4 d0 = *(const float4*)&cs[j2 * KC + off + mc];
      float4 d1 = *(const float4*)&cs[j2 * KC + off + mc + 4];
      *(uint4*)&ms[mrow2 * 40 + mc] = scale8(m2, d0, d1);
    }
  };
  floatx4 acc[10];
#pragma unroll
  for (int jt = 0; jt < 10; ++jt) acc[jt] = (floatx4){0.f, 0.f, 0.f, 0.f};
  prefetch(kbase);
  __syncthreads();   // cs ready
  const int nsteps = KC >> 5;  // 9
  for (int s = 0; s < nsteps; ++s) {
    commit(s * 32);
    __syncthreads();
    if (s + 1 < nsteps) prefetch(kbase + (s + 1) * 32);
    bf16x8 a = *(bf16x8*)&xs[(w * 16 + col) * 40 + quad * 8];
#pragma unroll
    for (int jt = 0; jt < 10; ++jt) {
      bf16x8 bb = *(bf16x8*)&ms[(jt * 16 + col) * 40 + quad * 8];
      acc[jt] = __builtin_amdgcn_mfma_f32_16x16x32_bf16(a, bb, acc[jt], 0, 0, 0);
    }
    __syncthreads();
  }
#pragma unroll
  for (int jt = 0; jt < 10; ++jt)
#pragma unroll
    for (int r = 0; r < 4; ++r) {
      int b = b0 + w * 16 + quad * 4 + r;
      sp[((size_t)blockIdx.y * B + b) * JU + jt * 16 + col] = acc[jt][r];
    }
}

// ---------------------------------------------------------------------------
// squash: s[b][ju] = sum_ks sp; msq over j (axis=1 quirk, faithful);
// v -> vT bf16 [ju][b]; out fp32 on last iter. Grid: 512 x 192.
// ---------------------------------------------------------------------------
__global__ __launch_bounds__(192) void squash_kernel(
    const float* __restrict__ sp, unsigned short* __restrict__ vT,
    float* __restrict__ out) {
  int b = blockIdx.x;
  int t = threadIdx.x;
  __shared__ float sv[JU];
  __shared__ float fac[US];
  float s = 0.0f;
  if (t < JU) {
#pragma unroll
    for (int k = 0; k < NSPLIT; ++k) s += sp[((size_t)k * B + b) * JU + t];
    sv[t] = s;
  }
  __syncthreads();
  if (t < US) {
    float m = 0.0f;
#pragma unroll
    for (int j = 0; j < NU; ++j) {
      float q = sv[j * US + t];
      m += q * q;
    }
    fac[t] = sqrtf(m) / (BETAC + m);
  }
  __syncthreads();
  if (t < JU) {
    float val = s * fac[t & 15];
    vT[(size_t)t * B + b] = f2bf(val);
    if (out) out[(size_t)b * JU + t] = val;
  }
}

// ---------------------------------------------------------------------------
// b_update (MFMA, dbuf): R[ki,ju] = sum_b xT[ki,b]*vT[ju,b] (K=b, split 2);
// bp[p][j][i] = (1/B) sum_u Wr[ki][ju]*R (16-lane shfl reduce, u=lane&15).
// Wr layout makes the epilogue read fully coalesced. Grid: (144, 2) x 256.
// ---------------------------------------------------------------------------
__global__ __launch_bounds__(256) void b_update_mfma(
    const unsigned short* __restrict__ xT, const unsigned short* __restrict__ vT,
    const float* __restrict__ Wr, float* __restrict__ bp) {
  int k = blockIdx.x / 18;
  int i0 = (blockIdx.x - k * 18) * 64;
  int bs = blockIdx.y;
  size_t ki0 = (size_t)k * IC + i0;
  int t = threadIdx.x;
  int w = t >> 6, lane = t & 63, col = lane & 15, quad = lane >> 4;
  __shared__ unsigned short xs[64 * 40];
  __shared__ unsigned short vs[160 * 40];
  int xrow = t >> 2, xc = (t & 3) * 8;
  int mrow0 = t >> 2, mrow1 = (t + 256) >> 2, mrow2 = (t + 512) >> 2;
  int mc = (t & 3) * 8;
  uint4 xv, m0, m1, m2;
  auto prefetch = [&](int c0) {
    xv = *(const uint4*)&xT[(ki0 + xrow) * B + c0 + xc];
    m0 = *(const uint4*)&vT[(size_t)mrow0 * B + c0 + mc];
    m1 = *(const uint4*)&vT[(size_t)mrow1 * B + c0 + mc];
    if (t < 128) m2 = *(const uint4*)&vT[(size_t)mrow2 * B + c0 + mc];
  };
  auto commit = [&]() {
    *(uint4*)&xs[xrow * 40 + xc] = xv;
    *(uint4*)&vs[mrow0 * 40 + mc] = m0;
    *(uint4*)&vs[mrow1 * 40 + mc] = m1;
    if (t < 128) *(uint4*)&vs[mrow2 * 40 + mc] = m2;
  };
  floatx4 acc[10];
#pragma unroll
  for (int jt = 0; jt < 10; ++jt) acc[jt] = (floatx4){0.f, 0.f, 0.f, 0.f};
  prefetch(bs * 256);
  for (int s = 0; s < 8; ++s) {
    commit();
    __syncthreads();
    if (s < 7) prefetch(bs * 256 + (s + 1) * 32);
    bf16x8 a = *(bf16x8*)&xs[(w * 16 + col) * 40 + quad * 8];
#pragma unroll
    for (int jt = 0; jt < 10; ++jt) {
      bf16x8 bb = *(bf16x8*)&vs[(jt * 16 + col) * 40 + quad * 8];
      acc[jt] = __builtin_amdgcn_mfma_f32_16x16x32_bf16(a, bb, acc[jt], 0, 0, 0);
    }
    __syncthreads();
  }
  int p = k * 2 + bs;
#pragma unroll
  for (int jt = 0; jt < 10; ++jt) {
#pragma unroll
    for (int r = 0; r < 4; ++r) {
      int i = i0 + w * 16 + quad * 4 + r;
      float wv = Wr[((size_t)k * IC + i) * JU + jt * 16 + col];
      float pr = wv * acc[jt][r];
      pr += __shfl_xor(pr, 1);
      pr += __shfl_xor(pr, 2);
      pr += __shfl_xor(pr, 4);
      pr += __shfl_xor(pr, 8);
      if (col == 0)
        bp[(size_t)p * (IC * NU) + jt * IC + i] = pr * (1.0f / (float)B);
    }
  }
}

// ---------------------------------------------------------------------------
// softmax over i (per j): bij[j][i] = sum_p bp[p][j][i]; cT[j][i] = softmax_i.
// Grid: 10 x 256. Coalesced over i.
// ---------------------------------------------------------------------------
__global__ __launch_bounds__(256) void softmax_c_kernel(
    const float* __restrict__ bp, float* __restrict__ cT) {
  int j = blockIdx.x;
  int t = threadIdx.x;
  __shared__ float bsum[IC];
  __shared__ float red[256];
  for (int i = t; i < IC; i += 256) {
    float s = 0.0f;
#pragma unroll
    for (int p = 0; p < 16; ++p) s += bp[(size_t)p * (IC * NU) + j * IC + i];
    bsum[i] = s;
  }
  __syncthreads();
  float m = -1e30f;
  for (int i = t; i < IC; i += 256) m = fmaxf(m, bsum[i]);
  red[t] = m;
  __syncthreads();
  for (int o = 128; o > 0; o >>= 1) {
    if (t < o) red[t] = fmaxf(red[t], red[t + o]);
    __syncthreads();
  }
  float mx = red[0];
  __syncthreads();
  float sm = 0.0f;
  for (int i = t; i < IC; i += 256) {
    float e = __expf(bsum[i] - mx);
    bsum[i] = e;
    sm += e;
  }
  red[t] = sm;
  __syncthreads();
  for (int o = 128; o > 0; o >>= 1) {
    if (t < o) red[t] += red[t + o];
    __syncthreads();
  }
  float inv = 1.0f / red[0];
  for (int i = t; i < IC; i += 256) cT[(size_t)j * IC + i] = bsum[i] * inv;
}

// ---------------------------------------------------------------------------
extern "C" void kernel_launch(void* const* d_in, const int* in_sizes, int n_in,
                              void* d_out, int out_size, void* d_ws,
                              size_t ws_size, hipStream_t stream) {
  const float* x = (const float*)d_in[0];   // (512, 8, 1152)
  const float* W = (const float*)d_in[1];   // (1152, 10, 16, 8)
  float* out = (float*)d_out;               // (512, 10, 16)

  // workspace layout (~39 MB total; harness provides ~268 MB)
  char* pws = (char*)d_ws;
  float* cT = (float*)pws;                     pws += (size_t)NU * IC * 4;
  float* bp = (float*)pws;                     pws += (size_t)16 * IC * NU * 4;
  float* sp = (float*)pws;                     pws += (size_t)NSPLIT * B * JU * 4;
  float* Wr = (float*)pws;                     pws += (size_t)KI * JU * 4;
  unsigned short* xb = (unsigned short*)pws;   pws += (size_t)B * KI * 2;
  unsigned short* xT = (unsigned short*)pws;   pws += (size_t)KI * B * 2;
  unsigned short* Wt = (unsigned short*)pws;   pws += (size_t)JU * KI * 2;
  unsigned short* vT = (unsigned short*)pws;

  prep_kernel<<<1152 + 144, 256, 0, stream>>>(x, W, xb, xT, Wt, Wr, cT);

  for (int it = 0; it < 3; ++it) {
    s_gemm_mfma<<<dim3(8, NSPLIT), 256, 0, stream>>>(xb, Wt, cT, sp);
    squash_kernel<<<B, 192, 0, stream>>>(sp, vT, (it == 2) ? out : nullptr);
    if (it < 2) {
      b_update_mfma<<<dim3(144, 2), 256, 0, stream>>>(xT, vT, Wr, bp);
      softmax_c_kernel<<<NU, 256, 0, stream>>>(bp, cT);
    }
  }
}